// Round 9
// baseline (219.325 us; speedup 1.0000x reference)
//
#include <hip/hip_runtime.h>

#define N_NODES 200000
#define N_EDGES 600000
#define F_IN 165
#define F_HID 128
#define KP 200    // bf16 row stride (ushorts) for xb/wt: 400B, 16B-aligned
#define NCVT 2048 // convert-portion blocks in k_cvt_count

typedef short short8 __attribute__((ext_vector_type(8)));
typedef float f32x4 __attribute__((ext_vector_type(4)));

__device__ __forceinline__ unsigned short f2bf(float f) {
  union { float f; unsigned int u; } v; v.f = f;
  unsigned int u = v.u;
  return (unsigned short)((u + 0x7FFFu + ((u >> 16) & 1u)) >> 16);  // RNE
}
__device__ __forceinline__ float bflo(unsigned int v) {
  union { unsigned int u; float f; } x; x.u = v << 16; return x.f;
}
__device__ __forceinline__ float bfhi(unsigned int v) {
  union { unsigned int u; float f; } x; x.u = v & 0xffff0000u; return x.f;
}

// ---- zero cnt + build W1^T bf16 [128][KP] (graph-replayed) ----
__global__ void k_zero(int* __restrict__ cnt, const float* __restrict__ W1,
                       unsigned short* __restrict__ wt) {
  int i = blockIdx.x * 256 + threadIdx.x;
  if (i < N_NODES) cnt[i] = 0;
  if (i < F_HID * KP) {
    int c = i / KP, k = i - c * KP;
    wt[i] = (k < F_IN) ? f2bf(W1[k * F_HID + c]) : (unsigned short)0;
  }
}

// ---- fused: x fp32 -> bf16 padded rows (streaming) || in-degree count (atomics) ----
__global__ void k_cvt_count(const float* __restrict__ x, unsigned short* __restrict__ xb,
                            const int* __restrict__ ei, int* __restrict__ cnt) {
  if (blockIdx.x >= NCVT) {
    int e = (blockIdx.x - NCVT) * 256 + threadIdx.x;
    if (e < N_EDGES) atomicAdd(&cnt[ei[N_EDGES + e]], 1);
    return;
  }
  int wid = (blockIdx.x * 256 + threadIdx.x) >> 6;  // 0..NCVT*4-1
  int lane = threadIdx.x & 63;
  for (int r = wid; r < N_NODES; r += NCVT * 4) {
    const float* xr = x + (long)r * F_IN;
    unsigned short* o = xb + (long)r * KP;
    #pragma unroll
    for (int it = 0; it < 4; ++it) {
      int c = lane + it * 64;
      if (c < KP) o[c] = (c < F_IN) ? f2bf(xr[c]) : (unsigned short)0;
    }
  }
}

// ---- CSR build ----
__global__ void k_scan1(const int* __restrict__ cnt, int* __restrict__ rowptr, int* __restrict__ bsum) {
  __shared__ int sd[256];
  int t = threadIdx.x;
  int idx = blockIdx.x * 256 + t;
  int v = (idx < N_NODES) ? cnt[idx] : 0;
  sd[t] = v; __syncthreads();
  #pragma unroll
  for (int off = 1; off < 256; off <<= 1) {
    int u = (t >= off) ? sd[t - off] : 0;
    __syncthreads();
    sd[t] += u;
    __syncthreads();
  }
  if (idx < N_NODES) rowptr[idx] = sd[t] - v;  // exclusive within block
  if (t == 255) bsum[blockIdx.x] = sd[t];
}

__global__ void k_scan2(int* __restrict__ bsum, int nb) {
  __shared__ int sd[1024];
  int t = threadIdx.x;
  int v = (t < nb) ? bsum[t] : 0;
  sd[t] = v; __syncthreads();
  for (int off = 1; off < 1024; off <<= 1) {
    int u = (t >= off) ? sd[t - off] : 0;
    __syncthreads();
    sd[t] += u;
    __syncthreads();
  }
  if (t < nb) bsum[t] = sd[t] - v;  // exclusive block offsets
}

__global__ void k_scan3(const int* __restrict__ cnt, const int* __restrict__ bsum,
                        int* __restrict__ rowptr, int* __restrict__ fill, float* __restrict__ dinv) {
  int idx = blockIdx.x * 256 + threadIdx.x;
  if (idx < N_NODES) {
    int rp = rowptr[idx] + bsum[blockIdx.x];
    rowptr[idx] = rp;
    fill[idx] = rp;  // mutable cursor for k_fill
    dinv[idx] = rsqrtf((float)(cnt[idx] + 1));  // deg = in-degree + self-loop >= 1
  }
  if (idx == 0) rowptr[N_NODES] = N_EDGES;
}

__global__ void k_fill(const int* __restrict__ ei, int* __restrict__ fill, int* __restrict__ srcl) {
  int e = blockIdx.x * 256 + threadIdx.x;
  if (e < N_EDGES) {
    int d = ei[N_EDGES + e];
    int s = ei[e];
    int slot = atomicAdd(&fill[d], 1);
    srcl[slot] = s;
  }
}

// ---- GEMM1 v5: no LDS, no barriers. Block's 4 waves = 4 col-quarters walking the
//      same (tile,rowgroup) units -> xb rows served from L1. W-quarter in 48 VGPRs.
//      Per unit/wave: 6 aligned dwordx4 xb loads + 12 MFMA + packed uint2 stores.
//      Swapped-operand MFMA epilogue layout verified rounds 5/8. ----
__global__ __launch_bounds__(256) void k_gemm1(const unsigned short* __restrict__ xb,
                                               const unsigned short* __restrict__ wt,
                                               const float* __restrict__ dinv,
                                               unsigned short* __restrict__ h16) {
  int tid = threadIdx.x;
  int lane = tid & 63;
  int cw = tid >> 6;       // col-quarter (fixed per wave)
  int lane15 = lane & 15;
  int kq = (lane >> 4) * 8;

  // hoist W-quarter: 2 col-blocks x 6 k-steps = 48 VGPRs
  short8 wf[2][6];
  {
    int c0 = cw * 32 + lane15;
    #pragma unroll
    for (int cb = 0; cb < 2; ++cb) {
      #pragma unroll
      for (int ks = 0; ks < 6; ++ks) {
        wf[cb][ks] = *(const short8*)(&wt[(c0 + cb * 16) * KP + ks * 32 + kq]);
      }
    }
  }

  // units: u = (tile, rowgroup), 6250*2 = 12500; all 4 waves of a block share u
  for (int u = blockIdx.x; u < 12500; u += gridDim.x) {
    int t = u >> 1, rg = u & 1;
    long r = (long)t * 32 + rg * 16 + lane15;
    const unsigned short* xr = xb + r * KP;  // 400B row, 16B-aligned

    short8 xf[6];
    #pragma unroll
    for (int ks = 0; ks < 6; ++ks) xf[ks] = *(const short8*)(xr + ks * 32 + kq);

    f32x4 acc[2];
    acc[0] = (f32x4){0.f, 0.f, 0.f, 0.f};
    acc[1] = (f32x4){0.f, 0.f, 0.f, 0.f};
    #pragma unroll
    for (int ks = 0; ks < 6; ++ks) {
      acc[0] = __builtin_amdgcn_mfma_f32_16x16x32_bf16(wf[0][ks], xf[ks], acc[0], 0, 0, 0);
      acc[1] = __builtin_amdgcn_mfma_f32_16x16x32_bf16(wf[1][ks], xf[ks], acc[1], 0, 0, 0);
    }

    // epilogue: lane owns row r; cols cw*32 + cb*16 + (lane>>4)*4 + j
    float dd = dinv[r];
    unsigned short* hp = &h16[r * F_HID + cw * 32 + (lane >> 4) * 4];
    #pragma unroll
    for (int cb = 0; cb < 2; ++cb) {
      unsigned int p0 = (unsigned int)f2bf(acc[cb][0] * dd) | ((unsigned int)f2bf(acc[cb][1] * dd) << 16);
      unsigned int p1 = (unsigned int)f2bf(acc[cb][2] * dd) | ((unsigned int)f2bf(acc[cb][3] * dd) << 16);
      uint2 pp; pp.x = p0; pp.y = p1;
      *(uint2*)(hp + cb * 16) = pp;
    }
  }
}

// ---- fused: agg1 (gather, 4-wide) + bias + relu + GEMM2 (128->2) ; output pre-scaled by dinv ----
__global__ __launch_bounds__(256) void k_agg1(const unsigned int* __restrict__ H,  // bf16x2 rows, 64 uints/node
                                              const float* __restrict__ dinv,
                                              const int* __restrict__ rowptr, const int* __restrict__ srcl,
                                              const float* __restrict__ b1, const float* __restrict__ W2,
                                              float* __restrict__ h2s) {
  int tid = threadIdx.x;
  int local = tid >> 6;
  int lane = tid & 63;
  int d = blockIdx.x * 4 + local;  // grid exact: 50000*4 = 200000

  unsigned int v = H[(long)d * 64 + lane];  // self (already dinv[d]-scaled)
  float acc0 = bflo(v), acc1 = bfhi(v);
  int r0 = rowptr[d], r1 = rowptr[d + 1];
  int n = r1 - r0;
  for (int b = 0; b < n; b += 4) {
    int i0 = r0 + b;
    bool m1 = b + 1 < n, m2 = b + 2 < n, m3 = b + 3 < n;
    int s0 = srcl[i0];
    int s1 = m1 ? srcl[i0 + 1] : s0;
    int s2 = m2 ? srcl[i0 + 2] : s0;
    int s3 = m3 ? srcl[i0 + 3] : s0;
    unsigned int v0 = H[(long)s0 * 64 + lane];
    unsigned int v1 = H[(long)s1 * 64 + lane];
    unsigned int v2 = H[(long)s2 * 64 + lane];
    unsigned int v3 = H[(long)s3 * 64 + lane];
    acc0 += bflo(v0);                            acc1 += bfhi(v0);
    acc0 = fmaf(m1 ? 1.f : 0.f, bflo(v1), acc0); acc1 = fmaf(m1 ? 1.f : 0.f, bfhi(v1), acc1);
    acc0 = fmaf(m2 ? 1.f : 0.f, bflo(v2), acc0); acc1 = fmaf(m2 ? 1.f : 0.f, bfhi(v2), acc1);
    acc0 = fmaf(m3 ? 1.f : 0.f, bflo(v3), acc0); acc1 = fmaf(m3 ? 1.f : 0.f, bfhi(v3), acc1);
  }
  float dd = dinv[d];
  float2 bb = ((const float2*)b1)[lane];
  float a0 = fmaxf(fmaf(acc0, dd, bb.x), 0.f);
  float a1 = fmaxf(fmaf(acc1, dd, bb.y), 0.f);
  float4 w2 = ((const float4*)W2)[lane];  // W2[2*lane][0..1], W2[2*lane+1][0..1]
  float p0 = a0 * w2.x + a1 * w2.z;
  float p1 = a0 * w2.y + a1 * w2.w;
  #pragma unroll
  for (int off = 32; off > 0; off >>= 1) {
    p0 += __shfl_down(p0, off);
    p1 += __shfl_down(p1, off);
  }
  if (lane == 0) ((float2*)h2s)[d] = make_float2(p0 * dd, p1 * dd);
}

// ---- agg2 over 2 features + bias (h2s pre-scaled by dinv) ----
__global__ void k_agg2(const float* __restrict__ h2s, const float* __restrict__ dinv,
                       const int* __restrict__ rowptr, const int* __restrict__ srcl,
                       const float* __restrict__ b2, float* __restrict__ out) {
  int d = blockIdx.x * 256 + threadIdx.x;
  if (d >= N_NODES) return;
  const float2* G = (const float2*)h2s;
  float2 g = G[d];
  float o0 = g.x, o1 = g.y;
  int r0 = rowptr[d], r1 = rowptr[d + 1];
  int n = r1 - r0;
  for (int b = 0; b < n; b += 4) {
    int i0 = r0 + b;
    bool m1 = b + 1 < n, m2 = b + 2 < n, m3 = b + 3 < n;
    int s0 = srcl[i0];
    int s1 = m1 ? srcl[i0 + 1] : s0;
    int s2 = m2 ? srcl[i0 + 2] : s0;
    int s3 = m3 ? srcl[i0 + 3] : s0;
    float2 g0 = G[s0], g1 = G[s1], g2 = G[s2], g3 = G[s3];
    o0 += g0.x;                          o1 += g0.y;
    o0 = fmaf(m1 ? 1.f : 0.f, g1.x, o0); o1 = fmaf(m1 ? 1.f : 0.f, g1.y, o1);
    o0 = fmaf(m2 ? 1.f : 0.f, g2.x, o0); o1 = fmaf(m2 ? 1.f : 0.f, g2.y, o1);
    o0 = fmaf(m3 ? 1.f : 0.f, g3.x, o0); o1 = fmaf(m3 ? 1.f : 0.f, g3.y, o1);
  }
  float dd = dinv[d];
  ((float2*)out)[d] = make_float2(fmaf(o0, dd, b2[0]), fmaf(o1, dd, b2[1]));
}

extern "C" void kernel_launch(void* const* d_in, const int* in_sizes, int n_in,
                              void* d_out, int out_size, void* d_ws, size_t ws_size,
                              hipStream_t stream) {
  const float* x  = (const float*)d_in[0];
  const int*   ei = (const int*)d_in[1];
  const float* W1 = (const float*)d_in[2];
  const float* b1 = (const float*)d_in[3];
  const float* W2 = (const float*)d_in[4];
  const float* b2 = (const float*)d_in[5];
  float* out = (float*)d_out;

  char* p = (char*)d_ws;
  size_t off = 0;
  auto take = [&](size_t bytes) -> void* {
    void* r = p + off;
    off += (bytes + 255) & ~(size_t)255;
    return r;
  };
  unsigned short* h16    = (unsigned short*)take((size_t)N_NODES * F_HID * 2);  // 51.2 MB, dinv-scaled bf16
  unsigned short* xb     = (unsigned short*)take((size_t)N_NODES * KP * 2);     // 80 MB, bf16 padded rows
  unsigned short* wt     = (unsigned short*)take((size_t)F_HID * KP * 2);
  float*          h2s    = (float*)take((size_t)N_NODES * 2 * 4);
  int*            cnt    = (int*)take((size_t)N_NODES * 4);
  int*            fill   = (int*)take((size_t)N_NODES * 4);
  int*            rowptr = (int*)take(((size_t)N_NODES + 1) * 4);
  int*            srcl   = (int*)take(((size_t)N_EDGES + 8) * 4);  // +8 pad for speculative unroll reads
  float*          dinv   = (float*)take((size_t)N_NODES * 4);
  int*            bsum   = (int*)take(4096);
  (void)ws_size; (void)in_sizes; (void)n_in; (void)out_size;

  int nbE = (N_EDGES + 255) / 256;
  int nbN = (N_NODES + 255) / 256;
  k_zero<<<nbN, 256, 0, stream>>>(cnt, W1, wt);
  k_cvt_count<<<NCVT + nbE, 256, 0, stream>>>(x, xb, ei, cnt);
  k_scan1<<<nbN, 256, 0, stream>>>(cnt, rowptr, bsum);
  k_scan2<<<1, 1024, 0, stream>>>(bsum, nbN);
  k_scan3<<<nbN, 256, 0, stream>>>(cnt, bsum, rowptr, fill, dinv);
  k_fill<<<nbE, 256, 0, stream>>>(ei, fill, srcl);
  k_gemm1<<<1024, 256, 0, stream>>>(xb, wt, dinv, h16);  // LDS-free, barrier-free
  k_agg1<<<N_NODES / 4, 256, 0, stream>>>((const unsigned int*)h16, dinv, rowptr, srcl, b1, W2, h2s);
  k_agg2<<<nbN, 256, 0, stream>>>(h2s, dinv, rowptr, srcl, b2, out);
}

// Round 10
// 210.440 us; speedup vs baseline: 1.0422x; 1.0422x over previous
//
#include <hip/hip_runtime.h>

#define N_NODES 200000
#define N_EDGES 600000
#define F_IN 165
#define F_HID 128
#define KP 200    // bf16 row stride (ushorts) for xb/wt: 400B, 16B-aligned
#define NCVT 2048 // convert-portion blocks in k_cvt_count

typedef short short8 __attribute__((ext_vector_type(8)));
typedef float f32x4 __attribute__((ext_vector_type(4)));

__device__ __forceinline__ unsigned short f2bf(float f) {
  union { float f; unsigned int u; } v; v.f = f;
  unsigned int u = v.u;
  return (unsigned short)((u + 0x7FFFu + ((u >> 16) & 1u)) >> 16);  // RNE
}
__device__ __forceinline__ float bflo(unsigned int v) {
  union { unsigned int u; float f; } x; x.u = v << 16; return x.f;
}
__device__ __forceinline__ float bfhi(unsigned int v) {
  union { unsigned int u; float f; } x; x.u = v & 0xffff0000u; return x.f;
}

// ---- zero cnt + build W1^T bf16 [128][KP] (graph-replayed) ----
__global__ void k_zero(int* __restrict__ cnt, const float* __restrict__ W1,
                       unsigned short* __restrict__ wt) {
  int i = blockIdx.x * 256 + threadIdx.x;
  if (i < N_NODES) cnt[i] = 0;
  if (i < F_HID * KP) {
    int c = i / KP, k = i - c * KP;
    wt[i] = (k < F_IN) ? f2bf(W1[k * F_HID + c]) : (unsigned short)0;
  }
}

// ---- fused: x fp32 -> bf16 padded rows (VECTORIZED: uint4 stores) || in-degree count ----
__global__ void k_cvt_count(const float* __restrict__ x, unsigned short* __restrict__ xb,
                            const int* __restrict__ ei, int* __restrict__ cnt) {
  if (blockIdx.x >= NCVT) {
    int e = (blockIdx.x - NCVT) * 256 + threadIdx.x;
    if (e < N_EDGES) atomicAdd(&cnt[ei[N_EDGES + e]], 1);
    return;
  }
  // each thread: 8 consecutive ushorts of xb -> one 16B store (covers pad with zeros)
  const int GROUPS = N_NODES * (KP / 8);  // 5,000,000
  for (int g = blockIdx.x * 256 + threadIdx.x; g < GROUPS; g += NCVT * 256) {
    int row = g / (KP / 8);
    int sub = g - row * (KP / 8);
    int c0 = sub * 8;
    const float* xr = x + (long)row * F_IN;
    unsigned int w[4];
    #pragma unroll
    for (int h = 0; h < 4; ++h) {
      int c = c0 + 2 * h;
      float f0 = (c     < F_IN) ? xr[c]     : 0.f;
      float f1 = (c + 1 < F_IN) ? xr[c + 1] : 0.f;
      w[h] = (unsigned int)f2bf(f0) | ((unsigned int)f2bf(f1) << 16);
    }
    uint4 o; o.x = w[0]; o.y = w[1]; o.z = w[2]; o.w = w[3];
    *(uint4*)(xb + (long)g * 8) = o;
  }
}

// ---- CSR build ----
__global__ void k_scan1(const int* __restrict__ cnt, int* __restrict__ rowptr, int* __restrict__ bsum) {
  __shared__ int sd[256];
  int t = threadIdx.x;
  int idx = blockIdx.x * 256 + t;
  int v = (idx < N_NODES) ? cnt[idx] : 0;
  sd[t] = v; __syncthreads();
  #pragma unroll
  for (int off = 1; off < 256; off <<= 1) {
    int u = (t >= off) ? sd[t - off] : 0;
    __syncthreads();
    sd[t] += u;
    __syncthreads();
  }
  if (idx < N_NODES) rowptr[idx] = sd[t] - v;  // exclusive within block
  if (t == 255) bsum[blockIdx.x] = sd[t];
}

__global__ void k_scan2(int* __restrict__ bsum, int nb) {
  __shared__ int sd[1024];
  int t = threadIdx.x;
  int v = (t < nb) ? bsum[t] : 0;
  sd[t] = v; __syncthreads();
  for (int off = 1; off < 1024; off <<= 1) {
    int u = (t >= off) ? sd[t - off] : 0;
    __syncthreads();
    sd[t] += u;
    __syncthreads();
  }
  if (t < nb) bsum[t] = sd[t] - v;  // exclusive block offsets
}

__global__ void k_scan3(const int* __restrict__ cnt, const int* __restrict__ bsum,
                        int* __restrict__ rowptr, int* __restrict__ fill, float* __restrict__ dinv) {
  int idx = blockIdx.x * 256 + threadIdx.x;
  if (idx < N_NODES) {
    int rp = rowptr[idx] + bsum[blockIdx.x];
    rowptr[idx] = rp;
    fill[idx] = rp;  // mutable cursor for k_fill
    dinv[idx] = rsqrtf((float)(cnt[idx] + 1));  // deg = in-degree + self-loop >= 1
  }
  if (idx == 0) rowptr[N_NODES] = N_EDGES;
}

__global__ void k_fill(const int* __restrict__ ei, int* __restrict__ fill, int* __restrict__ srcl) {
  int e = blockIdx.x * 256 + threadIdx.x;
  if (e < N_EDGES) {
    int d = ei[N_EDGES + e];
    int s = ei[e];
    int slot = atomicAdd(&fill[d], 1);
    srcl[slot] = s;
  }
}

// ---- GEMM1: no LDS, no barriers (round-9, validated). Block's 4 waves = 4 col-quarters
//      sharing (tile,rowgroup) units -> xb rows served from L1. W-quarter in 48 VGPRs. ----
__global__ __launch_bounds__(256) void k_gemm1(const unsigned short* __restrict__ xb,
                                               const unsigned short* __restrict__ wt,
                                               const float* __restrict__ dinv,
                                               unsigned short* __restrict__ h16) {
  int tid = threadIdx.x;
  int lane = tid & 63;
  int cw = tid >> 6;       // col-quarter (fixed per wave)
  int lane15 = lane & 15;
  int kq = (lane >> 4) * 8;

  short8 wf[2][6];
  {
    int c0 = cw * 32 + lane15;
    #pragma unroll
    for (int cb = 0; cb < 2; ++cb) {
      #pragma unroll
      for (int ks = 0; ks < 6; ++ks) {
        wf[cb][ks] = *(const short8*)(&wt[(c0 + cb * 16) * KP + ks * 32 + kq]);
      }
    }
  }

  for (int u = blockIdx.x; u < 12500; u += gridDim.x) {
    int t = u >> 1, rg = u & 1;
    long r = (long)t * 32 + rg * 16 + lane15;
    const unsigned short* xr = xb + r * KP;  // 400B row, 16B-aligned

    short8 xf[6];
    #pragma unroll
    for (int ks = 0; ks < 6; ++ks) xf[ks] = *(const short8*)(xr + ks * 32 + kq);

    f32x4 acc[2];
    acc[0] = (f32x4){0.f, 0.f, 0.f, 0.f};
    acc[1] = (f32x4){0.f, 0.f, 0.f, 0.f};
    #pragma unroll
    for (int ks = 0; ks < 6; ++ks) {
      acc[0] = __builtin_amdgcn_mfma_f32_16x16x32_bf16(wf[0][ks], xf[ks], acc[0], 0, 0, 0);
      acc[1] = __builtin_amdgcn_mfma_f32_16x16x32_bf16(wf[1][ks], xf[ks], acc[1], 0, 0, 0);
    }

    float dd = dinv[r];
    unsigned short* hp = &h16[r * F_HID + cw * 32 + (lane >> 4) * 4];
    #pragma unroll
    for (int cb = 0; cb < 2; ++cb) {
      unsigned int p0 = (unsigned int)f2bf(acc[cb][0] * dd) | ((unsigned int)f2bf(acc[cb][1] * dd) << 16);
      unsigned int p1 = (unsigned int)f2bf(acc[cb][2] * dd) | ((unsigned int)f2bf(acc[cb][3] * dd) << 16);
      uint2 pp; pp.x = p0; pp.y = p1;
      *(uint2*)(hp + cb * 16) = pp;
    }
  }
}

// ---- fused: agg1 + bias + relu + GEMM2 ; 32 lanes/node (uint2 = 8B/lane), 2 nodes/wave ----
__global__ __launch_bounds__(256) void k_agg1(const uint2* __restrict__ H2,  // 32 uint2/node
                                              const float* __restrict__ dinv,
                                              const int* __restrict__ rowptr, const int* __restrict__ srcl,
                                              const float* __restrict__ b1, const float* __restrict__ W2,
                                              float* __restrict__ h2s) {
  int tid = threadIdx.x;
  int l32 = tid & 31;
  int d = blockIdx.x * 8 + (tid >> 5);  // grid exact: 25000*8 = 200000

  uint2 v = H2[(long)d * 32 + l32];  // self (already dinv[d]-scaled)
  float acc0 = bflo(v.x), acc1 = bfhi(v.x), acc2 = bflo(v.y), acc3 = bfhi(v.y);
  int r0 = rowptr[d], r1 = rowptr[d + 1];
  int n = r1 - r0;
  for (int b = 0; b < n; b += 4) {
    int i0 = r0 + b;
    float f1 = (b + 1 < n) ? 1.f : 0.f;
    float f2 = (b + 2 < n) ? 1.f : 0.f;
    float f3 = (b + 3 < n) ? 1.f : 0.f;
    int s0 = srcl[i0];
    int s1 = (b + 1 < n) ? srcl[i0 + 1] : s0;
    int s2 = (b + 2 < n) ? srcl[i0 + 2] : s0;
    int s3 = (b + 3 < n) ? srcl[i0 + 3] : s0;
    uint2 v0 = H2[(long)s0 * 32 + l32];
    uint2 v1 = H2[(long)s1 * 32 + l32];
    uint2 v2 = H2[(long)s2 * 32 + l32];
    uint2 v3 = H2[(long)s3 * 32 + l32];
    acc0 += bflo(v0.x);               acc1 += bfhi(v0.x);
    acc2 += bflo(v0.y);               acc3 += bfhi(v0.y);
    acc0 = fmaf(f1, bflo(v1.x), acc0); acc1 = fmaf(f1, bfhi(v1.x), acc1);
    acc2 = fmaf(f1, bflo(v1.y), acc2); acc3 = fmaf(f1, bfhi(v1.y), acc3);
    acc0 = fmaf(f2, bflo(v2.x), acc0); acc1 = fmaf(f2, bfhi(v2.x), acc1);
    acc2 = fmaf(f2, bflo(v2.y), acc2); acc3 = fmaf(f2, bfhi(v2.y), acc3);
    acc0 = fmaf(f3, bflo(v3.x), acc0); acc1 = fmaf(f3, bfhi(v3.x), acc1);
    acc2 = fmaf(f3, bflo(v3.y), acc2); acc3 = fmaf(f3, bfhi(v3.y), acc3);
  }
  float dd = dinv[d];
  float4 bb = ((const float4*)b1)[l32];   // b1[4*l32 .. 4*l32+3]
  float a0 = fmaxf(fmaf(acc0, dd, bb.x), 0.f);
  float a1 = fmaxf(fmaf(acc1, dd, bb.y), 0.f);
  float a2 = fmaxf(fmaf(acc2, dd, bb.z), 0.f);
  float a3 = fmaxf(fmaf(acc3, dd, bb.w), 0.f);
  float4 w2a = ((const float4*)W2)[2 * l32];      // W2[c0][0..1], W2[c1][0..1]
  float4 w2b = ((const float4*)W2)[2 * l32 + 1];  // W2[c2][0..1], W2[c3][0..1]
  float p0 = a0 * w2a.x + a1 * w2a.z + a2 * w2b.x + a3 * w2b.z;
  float p1 = a0 * w2a.y + a1 * w2a.w + a2 * w2b.y + a3 * w2b.w;
  #pragma unroll
  for (int off = 16; off > 0; off >>= 1) {
    p0 += __shfl_down(p0, off, 32);
    p1 += __shfl_down(p1, off, 32);
  }
  if (l32 == 0) ((float2*)h2s)[d] = make_float2(p0 * dd, p1 * dd);
}

// ---- agg2 over 2 features + bias (h2s pre-scaled by dinv) ----
__global__ void k_agg2(const float* __restrict__ h2s, const float* __restrict__ dinv,
                       const int* __restrict__ rowptr, const int* __restrict__ srcl,
                       const float* __restrict__ b2, float* __restrict__ out) {
  int d = blockIdx.x * 256 + threadIdx.x;
  if (d >= N_NODES) return;
  const float2* G = (const float2*)h2s;
  float2 g = G[d];
  float o0 = g.x, o1 = g.y;
  int r0 = rowptr[d], r1 = rowptr[d + 1];
  int n = r1 - r0;
  for (int b = 0; b < n; b += 4) {
    int i0 = r0 + b;
    bool m1 = b + 1 < n, m2 = b + 2 < n, m3 = b + 3 < n;
    int s0 = srcl[i0];
    int s1 = m1 ? srcl[i0 + 1] : s0;
    int s2 = m2 ? srcl[i0 + 2] : s0;
    int s3 = m3 ? srcl[i0 + 3] : s0;
    float2 g0 = G[s0], g1 = G[s1], g2 = G[s2], g3 = G[s3];
    o0 += g0.x;                          o1 += g0.y;
    o0 = fmaf(m1 ? 1.f : 0.f, g1.x, o0); o1 = fmaf(m1 ? 1.f : 0.f, g1.y, o1);
    o0 = fmaf(m2 ? 1.f : 0.f, g2.x, o0); o1 = fmaf(m2 ? 1.f : 0.f, g2.y, o1);
    o0 = fmaf(m3 ? 1.f : 0.f, g3.x, o0); o1 = fmaf(m3 ? 1.f : 0.f, g3.y, o1);
  }
  float dd = dinv[d];
  ((float2*)out)[d] = make_float2(fmaf(o0, dd, b2[0]), fmaf(o1, dd, b2[1]));
}

extern "C" void kernel_launch(void* const* d_in, const int* in_sizes, int n_in,
                              void* d_out, int out_size, void* d_ws, size_t ws_size,
                              hipStream_t stream) {
  const float* x  = (const float*)d_in[0];
  const int*   ei = (const int*)d_in[1];
  const float* W1 = (const float*)d_in[2];
  const float* b1 = (const float*)d_in[3];
  const float* W2 = (const float*)d_in[4];
  const float* b2 = (const float*)d_in[5];
  float* out = (float*)d_out;

  char* p = (char*)d_ws;
  size_t off = 0;
  auto take = [&](size_t bytes) -> void* {
    void* r = p + off;
    off += (bytes + 255) & ~(size_t)255;
    return r;
  };
  unsigned short* h16    = (unsigned short*)take((size_t)N_NODES * F_HID * 2);  // 51.2 MB, dinv-scaled bf16
  unsigned short* xb     = (unsigned short*)take((size_t)N_NODES * KP * 2);     // 80 MB, bf16 padded rows
  unsigned short* wt     = (unsigned short*)take((size_t)F_HID * KP * 2);
  float*          h2s    = (float*)take((size_t)N_NODES * 2 * 4);
  int*            cnt    = (int*)take((size_t)N_NODES * 4);
  int*            fill   = (int*)take((size_t)N_NODES * 4);
  int*            rowptr = (int*)take(((size_t)N_NODES + 1) * 4);
  int*            srcl   = (int*)take(((size_t)N_EDGES + 8) * 4);  // +8 pad for speculative unroll reads
  float*          dinv   = (float*)take((size_t)N_NODES * 4);
  int*            bsum   = (int*)take(4096);
  (void)ws_size; (void)in_sizes; (void)n_in; (void)out_size;

  int nbE = (N_EDGES + 255) / 256;
  int nbN = (N_NODES + 255) / 256;
  k_zero<<<nbN, 256, 0, stream>>>(cnt, W1, wt);
  k_cvt_count<<<NCVT + nbE, 256, 0, stream>>>(x, xb, ei, cnt);
  k_scan1<<<nbN, 256, 0, stream>>>(cnt, rowptr, bsum);
  k_scan2<<<1, 1024, 0, stream>>>(bsum, nbN);
  k_scan3<<<nbN, 256, 0, stream>>>(cnt, bsum, rowptr, fill, dinv);
  k_fill<<<nbE, 256, 0, stream>>>(ei, fill, srcl);
  k_gemm1<<<1024, 256, 0, stream>>>(xb, wt, dinv, h16);  // LDS-free, barrier-free
  k_agg1<<<N_NODES / 8, 256, 0, stream>>>((const uint2*)h16, dinv, rowptr, srcl, b1, W2, h2s);
  k_agg2<<<nbN, 256, 0, stream>>>(h2s, dinv, rowptr, srcl, b2, out);
}

// Round 11
// 197.205 us; speedup vs baseline: 1.1122x; 1.0671x over previous
//
#include <hip/hip_runtime.h>

#define N_NODES 200000
#define N_EDGES 600000
#define F_IN 165
#define F_HID 128
#define KP 200    // bf16 row stride (ushorts) for xb/wt: 400B, 16B-aligned
#define NCVT 2048 // convert-portion blocks in k_cvt_count

typedef short short8 __attribute__((ext_vector_type(8)));
typedef float f32x4 __attribute__((ext_vector_type(4)));

__device__ __forceinline__ unsigned int f2bf(float f) {
  union { float f; unsigned int u; } v; v.f = f;
  unsigned int u = v.u;
  return (u + 0x7FFFu + ((u >> 16) & 1u)) >> 16;  // RNE
}
__device__ __forceinline__ float bflo(unsigned int v) {
  union { unsigned int u; float f; } x; x.u = v << 16; return x.f;
}
__device__ __forceinline__ float bfhi(unsigned int v) {
  union { unsigned int u; float f; } x; x.u = v & 0xffff0000u; return x.f;
}

// ---- zero cnt + build W1^T bf16 [128][KP] (graph-replayed) ----
__global__ void k_zero(int* __restrict__ cnt, const float* __restrict__ W1,
                       unsigned short* __restrict__ wt) {
  int i = blockIdx.x * 256 + threadIdx.x;
  if (i < N_NODES) cnt[i] = 0;
  if (i < F_HID * KP) {
    int c = i / KP, k = i - c * KP;
    wt[i] = (k < F_IN) ? (unsigned short)f2bf(W1[k * F_HID + c]) : (unsigned short)0;
  }
}

// ---- fused: x fp32 -> bf16 padded rows (wave-per-row, shuffle-aligned) || in-degree count ----
// Row r bytes [660r,660r+660) sit in the aligned float4 window starting at 660r-4s, s=r&3.
// Lanes 0..41 load aligned float4; 12 uniform shfl re-align; lanes 0..24 store aligned uint4.
__global__ void k_cvt_count(const float* __restrict__ x, unsigned short* __restrict__ xb,
                            const int* __restrict__ ei, int* __restrict__ cnt) {
  if (blockIdx.x >= NCVT) {
    int e = (blockIdx.x - NCVT) * 256 + threadIdx.x;
    if (e < N_EDGES) atomicAdd(&cnt[ei[N_EDGES + e]], 1);
    return;
  }
  int lane = threadIdx.x & 63;
  int wid = (blockIdx.x * 256 + threadIdx.x) >> 6;
  int m2 = 2 * lane;
  for (int r = wid; r < N_NODES; r += NCVT * 4) {
    int s = r & 3;                                       // wave-uniform
    const float4* src = (const float4*)x + (((long)165 * r - s) >> 2);  // 165r-s divisible by 4
    float4 A = make_float4(0.f, 0.f, 0.f, 0.f);
    if (lane < 42) A = src[lane];                        // covers row floats [-s, 167-s]
    float4 P, Q, R4;
    P.x = __shfl(A.x, m2);     P.y = __shfl(A.y, m2);     P.z = __shfl(A.z, m2);     P.w = __shfl(A.w, m2);
    Q.x = __shfl(A.x, m2 + 1); Q.y = __shfl(A.y, m2 + 1); Q.z = __shfl(A.z, m2 + 1); Q.w = __shfl(A.w, m2 + 1);
    R4.x = __shfl(A.x, m2 + 2); R4.y = __shfl(A.y, m2 + 2); R4.z = __shfl(A.z, m2 + 2); R4.w = __shfl(A.w, m2 + 2);
    float e8[8];
    if (s == 0)      { e8[0]=P.x; e8[1]=P.y; e8[2]=P.z; e8[3]=P.w; e8[4]=Q.x; e8[5]=Q.y; e8[6]=Q.z; e8[7]=Q.w; }
    else if (s == 1) { e8[0]=P.y; e8[1]=P.z; e8[2]=P.w; e8[3]=Q.x; e8[4]=Q.y; e8[5]=Q.z; e8[6]=Q.w; e8[7]=R4.x; }
    else if (s == 2) { e8[0]=P.z; e8[1]=P.w; e8[2]=Q.x; e8[3]=Q.y; e8[4]=Q.z; e8[5]=Q.w; e8[6]=R4.x; e8[7]=R4.y; }
    else             { e8[0]=P.w; e8[1]=Q.x; e8[2]=Q.y; e8[3]=Q.z; e8[4]=Q.w; e8[5]=R4.x; e8[6]=R4.y; e8[7]=R4.z; }
    int c0 = 8 * lane;
    #pragma unroll
    for (int t = 0; t < 8; ++t) if (c0 + t >= F_IN) e8[t] = 0.f;
    if (lane < KP / 8) {  // lanes 0..24 store; pad cols [165,200) are zeros
      uint4 o;
      o.x = f2bf(e8[0]) | (f2bf(e8[1]) << 16);
      o.y = f2bf(e8[2]) | (f2bf(e8[3]) << 16);
      o.z = f2bf(e8[4]) | (f2bf(e8[5]) << 16);
      o.w = f2bf(e8[6]) | (f2bf(e8[7]) << 16);
      *(uint4*)(xb + (long)r * KP + c0) = o;  // byte addr 400r+16*lane: 16B-aligned
    }
  }
}

// ---- CSR build ----
__global__ void k_scan1(const int* __restrict__ cnt, int* __restrict__ rowptr, int* __restrict__ bsum) {
  __shared__ int sd[256];
  int t = threadIdx.x;
  int idx = blockIdx.x * 256 + t;
  int v = (idx < N_NODES) ? cnt[idx] : 0;
  sd[t] = v; __syncthreads();
  #pragma unroll
  for (int off = 1; off < 256; off <<= 1) {
    int u = (t >= off) ? sd[t - off] : 0;
    __syncthreads();
    sd[t] += u;
    __syncthreads();
  }
  if (idx < N_NODES) rowptr[idx] = sd[t] - v;  // exclusive within block
  if (t == 255) bsum[blockIdx.x] = sd[t];
}

__global__ void k_scan2(int* __restrict__ bsum, int nb) {
  __shared__ int sd[1024];
  int t = threadIdx.x;
  int v = (t < nb) ? bsum[t] : 0;
  sd[t] = v; __syncthreads();
  for (int off = 1; off < 1024; off <<= 1) {
    int u = (t >= off) ? sd[t - off] : 0;
    __syncthreads();
    sd[t] += u;
    __syncthreads();
  }
  if (t < nb) bsum[t] = sd[t] - v;  // exclusive block offsets
}

__global__ void k_scan3(const int* __restrict__ cnt, const int* __restrict__ bsum,
                        int* __restrict__ rowptr, int* __restrict__ fill, float* __restrict__ dinv) {
  int idx = blockIdx.x * 256 + threadIdx.x;
  if (idx < N_NODES) {
    int rp = rowptr[idx] + bsum[blockIdx.x];
    rowptr[idx] = rp;
    fill[idx] = rp;  // mutable cursor for k_fill
    dinv[idx] = rsqrtf((float)(cnt[idx] + 1));  // deg = in-degree + self-loop >= 1
  }
  if (idx == 0) rowptr[N_NODES] = N_EDGES;
}

__global__ void k_fill(const int* __restrict__ ei, int* __restrict__ fill, int* __restrict__ srcl) {
  int e = blockIdx.x * 256 + threadIdx.x;
  if (e < N_EDGES) {
    int d = ei[N_EDGES + e];
    int s = ei[e];
    int slot = atomicAdd(&fill[d], 1);
    srcl[slot] = s;
  }
}

// ---- GEMM1: no LDS, no barriers (round-9, validated). Block's 4 waves = 4 col-quarters
//      sharing (tile,rowgroup) units -> xb rows served from L1. W-quarter in 48 VGPRs. ----
__global__ __launch_bounds__(256) void k_gemm1(const unsigned short* __restrict__ xb,
                                               const unsigned short* __restrict__ wt,
                                               const float* __restrict__ dinv,
                                               unsigned short* __restrict__ h16) {
  int tid = threadIdx.x;
  int lane = tid & 63;
  int cw = tid >> 6;       // col-quarter (fixed per wave)
  int lane15 = lane & 15;
  int kq = (lane >> 4) * 8;

  short8 wf[2][6];
  {
    int c0 = cw * 32 + lane15;
    #pragma unroll
    for (int cb = 0; cb < 2; ++cb) {
      #pragma unroll
      for (int ks = 0; ks < 6; ++ks) {
        wf[cb][ks] = *(const short8*)(&wt[(c0 + cb * 16) * KP + ks * 32 + kq]);
      }
    }
  }

  for (int u = blockIdx.x; u < 12500; u += gridDim.x) {
    int t = u >> 1, rg = u & 1;
    long r = (long)t * 32 + rg * 16 + lane15;
    const unsigned short* xr = xb + r * KP;  // 400B row, 16B-aligned

    short8 xf[6];
    #pragma unroll
    for (int ks = 0; ks < 6; ++ks) xf[ks] = *(const short8*)(xr + ks * 32 + kq);

    f32x4 acc[2];
    acc[0] = (f32x4){0.f, 0.f, 0.f, 0.f};
    acc[1] = (f32x4){0.f, 0.f, 0.f, 0.f};
    #pragma unroll
    for (int ks = 0; ks < 6; ++ks) {
      acc[0] = __builtin_amdgcn_mfma_f32_16x16x32_bf16(wf[0][ks], xf[ks], acc[0], 0, 0, 0);
      acc[1] = __builtin_amdgcn_mfma_f32_16x16x32_bf16(wf[1][ks], xf[ks], acc[1], 0, 0, 0);
    }

    float dd = dinv[r];
    unsigned short* hp = &h16[r * F_HID + cw * 32 + (lane >> 4) * 4];
    #pragma unroll
    for (int cb = 0; cb < 2; ++cb) {
      unsigned int p0 = f2bf(acc[cb][0] * dd) | (f2bf(acc[cb][1] * dd) << 16);
      unsigned int p1 = f2bf(acc[cb][2] * dd) | (f2bf(acc[cb][3] * dd) << 16);
      uint2 pp; pp.x = p0; pp.y = p1;
      *(uint2*)(hp + cb * 16) = pp;
    }
  }
}

// ---- fused: agg1 + bias + relu + GEMM2 ; 32 lanes/node (uint2 = 8B/lane), 2 nodes/wave ----
__global__ __launch_bounds__(256) void k_agg1(const uint2* __restrict__ H2,  // 32 uint2/node
                                              const float* __restrict__ dinv,
                                              const int* __restrict__ rowptr, const int* __restrict__ srcl,
                                              const float* __restrict__ b1, const float* __restrict__ W2,
                                              float* __restrict__ h2s) {
  int tid = threadIdx.x;
  int l32 = tid & 31;
  int d = blockIdx.x * 8 + (tid >> 5);  // grid exact: 25000*8 = 200000

  uint2 v = H2[(long)d * 32 + l32];  // self (already dinv[d]-scaled)
  float acc0 = bflo(v.x), acc1 = bfhi(v.x), acc2 = bflo(v.y), acc3 = bfhi(v.y);
  int r0 = rowptr[d], r1 = rowptr[d + 1];
  int n = r1 - r0;
  for (int b = 0; b < n; b += 4) {
    int i0 = r0 + b;
    float f1 = (b + 1 < n) ? 1.f : 0.f;
    float f2 = (b + 2 < n) ? 1.f : 0.f;
    float f3 = (b + 3 < n) ? 1.f : 0.f;
    int s0 = srcl[i0];
    int s1 = (b + 1 < n) ? srcl[i0 + 1] : s0;
    int s2 = (b + 2 < n) ? srcl[i0 + 2] : s0;
    int s3 = (b + 3 < n) ? srcl[i0 + 3] : s0;
    uint2 v0 = H2[(long)s0 * 32 + l32];
    uint2 v1 = H2[(long)s1 * 32 + l32];
    uint2 v2 = H2[(long)s2 * 32 + l32];
    uint2 v3 = H2[(long)s3 * 32 + l32];
    acc0 += bflo(v0.x);               acc1 += bfhi(v0.x);
    acc2 += bflo(v0.y);               acc3 += bfhi(v0.y);
    acc0 = fmaf(f1, bflo(v1.x), acc0); acc1 = fmaf(f1, bfhi(v1.x), acc1);
    acc2 = fmaf(f1, bflo(v1.y), acc2); acc3 = fmaf(f1, bfhi(v1.y), acc3);
    acc0 = fmaf(f2, bflo(v2.x), acc0); acc1 = fmaf(f2, bfhi(v2.x), acc1);
    acc2 = fmaf(f2, bflo(v2.y), acc2); acc3 = fmaf(f2, bfhi(v2.y), acc3);
    acc0 = fmaf(f3, bflo(v3.x), acc0); acc1 = fmaf(f3, bfhi(v3.x), acc1);
    acc2 = fmaf(f3, bflo(v3.y), acc2); acc3 = fmaf(f3, bfhi(v3.y), acc3);
  }
  float dd = dinv[d];
  float4 bb = ((const float4*)b1)[l32];   // b1[4*l32 .. 4*l32+3]
  float a0 = fmaxf(fmaf(acc0, dd, bb.x), 0.f);
  float a1 = fmaxf(fmaf(acc1, dd, bb.y), 0.f);
  float a2 = fmaxf(fmaf(acc2, dd, bb.z), 0.f);
  float a3 = fmaxf(fmaf(acc3, dd, bb.w), 0.f);
  float4 w2a = ((const float4*)W2)[2 * l32];      // W2[c0][0..1], W2[c1][0..1]
  float4 w2b = ((const float4*)W2)[2 * l32 + 1];  // W2[c2][0..1], W2[c3][0..1]
  float p0 = a0 * w2a.x + a1 * w2a.z + a2 * w2b.x + a3 * w2b.z;
  float p1 = a0 * w2a.y + a1 * w2a.w + a2 * w2b.y + a3 * w2b.w;
  #pragma unroll
  for (int off = 16; off > 0; off >>= 1) {
    p0 += __shfl_down(p0, off, 32);
    p1 += __shfl_down(p1, off, 32);
  }
  if (l32 == 0) ((float2*)h2s)[d] = make_float2(p0 * dd, p1 * dd);
}

// ---- agg2 over 2 features + bias (h2s pre-scaled by dinv) ----
__global__ void k_agg2(const float* __restrict__ h2s, const float* __restrict__ dinv,
                       const int* __restrict__ rowptr, const int* __restrict__ srcl,
                       const float* __restrict__ b2, float* __restrict__ out) {
  int d = blockIdx.x * 256 + threadIdx.x;
  if (d >= N_NODES) return;
  const float2* G = (const float2*)h2s;
  float2 g = G[d];
  float o0 = g.x, o1 = g.y;
  int r0 = rowptr[d], r1 = rowptr[d + 1];
  int n = r1 - r0;
  for (int b = 0; b < n; b += 4) {
    int i0 = r0 + b;
    bool m1 = b + 1 < n, m2 = b + 2 < n, m3 = b + 3 < n;
    int s0 = srcl[i0];
    int s1 = m1 ? srcl[i0 + 1] : s0;
    int s2 = m2 ? srcl[i0 + 2] : s0;
    int s3 = m3 ? srcl[i0 + 3] : s0;
    float2 g0 = G[s0], g1 = G[s1], g2 = G[s2], g3 = G[s3];
    o0 += g0.x;                          o1 += g0.y;
    o0 = fmaf(m1 ? 1.f : 0.f, g1.x, o0); o1 = fmaf(m1 ? 1.f : 0.f, g1.y, o1);
    o0 = fmaf(m2 ? 1.f : 0.f, g2.x, o0); o1 = fmaf(m2 ? 1.f : 0.f, g2.y, o1);
    o0 = fmaf(m3 ? 1.f : 0.f, g3.x, o0); o1 = fmaf(m3 ? 1.f : 0.f, g3.y, o1);
  }
  float dd = dinv[d];
  ((float2*)out)[d] = make_float2(fmaf(o0, dd, b2[0]), fmaf(o1, dd, b2[1]));
}

extern "C" void kernel_launch(void* const* d_in, const int* in_sizes, int n_in,
                              void* d_out, int out_size, void* d_ws, size_t ws_size,
                              hipStream_t stream) {
  const float* x  = (const float*)d_in[0];
  const int*   ei = (const int*)d_in[1];
  const float* W1 = (const float*)d_in[2];
  const float* b1 = (const float*)d_in[3];
  const float* W2 = (const float*)d_in[4];
  const float* b2 = (const float*)d_in[5];
  float* out = (float*)d_out;

  char* p = (char*)d_ws;
  size_t off = 0;
  auto take = [&](size_t bytes) -> void* {
    void* r = p + off;
    off += (bytes + 255) & ~(size_t)255;
    return r;
  };
  unsigned short* h16    = (unsigned short*)take((size_t)N_NODES * F_HID * 2);  // 51.2 MB, dinv-scaled bf16
  unsigned short* xb     = (unsigned short*)take((size_t)N_NODES * KP * 2);     // 80 MB, bf16 padded rows
  unsigned short* wt     = (unsigned short*)take((size_t)F_HID * KP * 2);
  float*          h2s    = (float*)take((size_t)N_NODES * 2 * 4);
  int*            cnt    = (int*)take((size_t)N_NODES * 4);
  int*            fill   = (int*)take((size_t)N_NODES * 4);
  int*            rowptr = (int*)take(((size_t)N_NODES + 1) * 4);
  int*            srcl   = (int*)take(((size_t)N_EDGES + 8) * 4);  // +8 pad for speculative unroll reads
  float*          dinv   = (float*)take((size_t)N_NODES * 4);
  int*            bsum   = (int*)take(4096);
  (void)ws_size; (void)in_sizes; (void)n_in; (void)out_size;

  int nbE = (N_EDGES + 255) / 256;
  int nbN = (N_NODES + 255) / 256;
  k_zero<<<nbN, 256, 0, stream>>>(cnt, W1, wt);
  k_cvt_count<<<NCVT + nbE, 256, 0, stream>>>(x, xb, ei, cnt);
  k_scan1<<<nbN, 256, 0, stream>>>(cnt, rowptr, bsum);
  k_scan2<<<1, 1024, 0, stream>>>(bsum, nbN);
  k_scan3<<<nbN, 256, 0, stream>>>(cnt, bsum, rowptr, fill, dinv);
  k_fill<<<nbE, 256, 0, stream>>>(ei, fill, srcl);
  k_gemm1<<<1024, 256, 0, stream>>>(xb, wt, dinv, h16);  // LDS-free, barrier-free
  k_agg1<<<N_NODES / 8, 256, 0, stream>>>((const uint2*)h16, dinv, rowptr, srcl, b1, W2, h2s);
  k_agg2<<<nbN, 256, 0, stream>>>(h2s, dinv, rowptr, srcl, b2, out);
}